// Round 3
// baseline (486.833 us; speedup 1.0000x reference)
//
#include <hip/hip_runtime.h>

// LieTransport semi-Lagrangian advection, v3.
// B=4, C=64, H=128, W=128, R=16, fp32.
//
// v2 post-mortem: FETCH 430->127 MB (XCD plane-blocking + NT stores worked;
// L3 keeps h_prev resident), occupancy 29->73%, but dur only 240->188 us.
// VGPR_Count=24 => the compiler serialized the 8 gathers (needs 32 VGPRs of
// landing space); ~2 loads in flight per wave => latency-bound.
//
// v3: widen per-thread MLP to 16 independent float4 gathers:
//   - each thread handles PIX=2 pixels x CH=2 channels (keeps the proven 2 MB
//     per-XCD plane-group L2 footprint; CH=4 would hit exactly 4 MB = L2 size)
//   - all 16 loads issued into named registers before any blend
//   - 32-bit element offsets off a block-uniform base => SGPR-base+voffset
//     addressing, cheap address VGPRs
//   - __launch_bounds__(256,4): allow up to 128 VGPRs (est ~100)
// Everything else (XCD swizzle, NT stores, coord math) unchanged.

constexpr int B = 4, C = 64, H = 128, W = 128, R = 16;
constexpr int CH   = 2;                    // channels per thread
constexpr int PIX  = 2;                    // pixels per thread
constexpr int PPB  = 64 * PIX;             // pixels per block = 128
constexpr int NXCD = 8;
constexpr int TILES  = (H * W) / PPB;      // 128 tiles per plane-group
constexpr int GROUPS = (B * C) / CH;       // 128 plane-groups
// grid = GROUPS * TILES = 16384 blocks

typedef float nfloat4 __attribute__((ext_vector_type(4)));

__global__ __launch_bounds__(256, 4) void lie_transport_kernel(
    const float* __restrict__ h_prev,
    const float* __restrict__ flow,
    const float* __restrict__ dt,
    float* __restrict__ out) {
  // ---- block swizzle: physical block -> (xcd, group-on-xcd, tile) ----
  const int blk  = blockIdx.x;
  const int xcd  = blk & (NXCD - 1);        // hw round-robin target XCD
  const int seq  = blk >> 3;                // dispatch order within this XCD
  const int gidx = seq / TILES;             // 0..15
  const int tile = seq & (TILES - 1);       // 0..127
  const int pg   = gidx * NXCD + xcd;       // global plane-group 0..127
  const int b    = pg >> 5;                 // pg / (C/CH)
  const int c0   = (pg & 31) * CH;

  const int t   = threadIdx.x;
  const int r4  = (t & 3) * 4;              // float4 chunk within R
  const int p   = t >> 2;                   // pixel-slot within tile (0..63)

  const float dtb = dt[b];
  const float* fl = flow + (size_t)b * 2 * H * W;

  // ---- per-pixel coordinate math for PIX pixels ----
  unsigned o00[PIX], o01[PIX], o10[PIX], o11[PIX], oou[PIX];
  float w00[PIX], w01[PIX], w10[PIX], w11[PIX];
#pragma unroll
  for (int q = 0; q < PIX; ++q) {
    const int pix = tile * PPB + q * 64 + p;   // 0..16383 within plane
    const int x = pix & (W - 1);
    const int y = pix >> 7;

    const float f0 = fl[y * W + x];
    const float f1 = fl[H * W + y * W + x];

    const float bx = -1.0f + 2.0f * (float)x / (float)(W - 1);
    const float by = -1.0f + 2.0f * (float)y / (float)(H - 1);
    const float gx = bx - f0 * dtb;
    const float gy = by - f1 * dtb;
    float ix = ((gx + 1.0f) * (float)W - 1.0f) * 0.5f;
    float iy = ((gy + 1.0f) * (float)H - 1.0f) * 0.5f;
    ix = fminf(fmaxf(ix, 0.0f), (float)(W - 1));
    iy = fminf(fmaxf(iy, 0.0f), (float)(H - 1));

    const float x0f = floorf(ix);
    const float y0f = floorf(iy);
    const float wx = ix - x0f;
    const float wy = iy - y0f;
    const int x0 = min(max((int)x0f, 0), W - 1);
    const int x1 = min(x0 + 1, W - 1);
    const int y0 = min(max((int)y0f, 0), H - 1);
    const int y1 = min(y0 + 1, W - 1);

    w00[q] = (1.0f - wx) * (1.0f - wy);
    w01[q] = wx * (1.0f - wy);
    w10[q] = (1.0f - wx) * wy;
    w11[q] = wx * wy;

    o00[q] = (unsigned)(y0 * W + x0) * R + r4;
    o01[q] = (unsigned)(y0 * W + x1) * R + r4;
    o10[q] = (unsigned)(y1 * W + x0) * R + r4;
    o11[q] = (unsigned)(y1 * W + x1) * R + r4;
    oou[q] = (unsigned)pix * R + r4;
  }

  const size_t chwr = (size_t)H * W * R;
  const size_t base = ((size_t)b * C + c0) * chwr;   // block-uniform -> SGPR

  // ---- 16 independent gathers, all issued before any use ----
  nfloat4 v[PIX][CH][4];
#pragma unroll
  for (int q = 0; q < PIX; ++q) {
#pragma unroll
    for (int cc = 0; cc < CH; ++cc) {
      const float* cb = h_prev + base + (size_t)cc * chwr;
      v[q][cc][0] = *(const nfloat4*)(cb + o00[q]);
      v[q][cc][1] = *(const nfloat4*)(cb + o01[q]);
      v[q][cc][2] = *(const nfloat4*)(cb + o10[q]);
      v[q][cc][3] = *(const nfloat4*)(cb + o11[q]);
    }
  }

  // ---- blend + coalesced NT stores ----
#pragma unroll
  for (int q = 0; q < PIX; ++q) {
#pragma unroll
    for (int cc = 0; cc < CH; ++cc) {
      nfloat4 r = v[q][cc][0] * w00[q] + v[q][cc][1] * w01[q] +
                  v[q][cc][2] * w10[q] + v[q][cc][3] * w11[q];
      __builtin_nontemporal_store(
          r, (nfloat4*)(out + base + (size_t)cc * chwr + oou[q]));
    }
  }
}

extern "C" void kernel_launch(void* const* d_in, const int* in_sizes, int n_in,
                              void* d_out, int out_size, void* d_ws, size_t ws_size,
                              hipStream_t stream) {
  const float* h_prev = (const float*)d_in[0];
  const float* flow   = (const float*)d_in[1];
  const float* dt     = (const float*)d_in[2];
  float* outp = (float*)d_out;

  const int grid = GROUPS * TILES;   // 16384 blocks
  lie_transport_kernel<<<grid, 256, 0, stream>>>(h_prev, flow, dt, outp);
}

// Round 4
// 480.036 us; speedup vs baseline: 1.0142x; 1.0142x over previous
//
#include <hip/hip_runtime.h>

// LieTransport semi-Lagrangian advection, v4.
// B=4, C=64, H=128, W=128, R=16, fp32.
//
// v3 post-mortem: predicted VGPR ~100 (16 loads in flight), got VGPR=32 --
// the compiler re-serialized the gathers to minimize register pressure, so
// the MLP hypothesis was never actually tested. dur stuck at 190 us with
// VALUBusy 9%, HBM 26%, occupancy 85%: nothing saturated = latency-bound.
//
// v4 = v3 + __builtin_amdgcn_sched_barrier(0) between the 16-load cluster
// and the blend/store cluster. Nothing may cross the fence, so all 16
// dwordx4 destinations are simultaneously live -> allocator must give ~64
// landing VGPRs; waitcnts become counted (vmcnt(12/8/4)) instead of drains.
// This forces the per-wave MLP that v3 failed to deliver.
//
// Keep: CH=2 x PIX=2 per thread, XCD plane-group swizzle (2 MB L2 footprint,
// FETCH 430->127 MB win), NT stores, block-uniform SGPR base + 32-bit
// voffsets.

constexpr int B = 4, C = 64, H = 128, W = 128, R = 16;
constexpr int CH   = 2;                    // channels per thread
constexpr int PIX  = 2;                    // pixels per thread
constexpr int PPB  = 64 * PIX;             // pixels per block = 128
constexpr int NXCD = 8;
constexpr int TILES  = (H * W) / PPB;      // 128 tiles per plane-group
constexpr int GROUPS = (B * C) / CH;       // 128 plane-groups
// grid = GROUPS * TILES = 16384 blocks

typedef float nfloat4 __attribute__((ext_vector_type(4)));

__global__ __launch_bounds__(256, 4) void lie_transport_kernel(
    const float* __restrict__ h_prev,
    const float* __restrict__ flow,
    const float* __restrict__ dt,
    float* __restrict__ out) {
  // ---- block swizzle: physical block -> (xcd, group-on-xcd, tile) ----
  const int blk  = blockIdx.x;
  const int xcd  = blk & (NXCD - 1);        // hw round-robin target XCD
  const int seq  = blk >> 3;                // dispatch order within this XCD
  const int gidx = seq / TILES;             // 0..15
  const int tile = seq & (TILES - 1);       // 0..127
  const int pg   = gidx * NXCD + xcd;       // global plane-group 0..127
  const int b    = pg >> 5;                 // pg / (C/CH)
  const int c0   = (pg & 31) * CH;

  const int t   = threadIdx.x;
  const int r4  = (t & 3) * 4;              // float4 chunk within R
  const int p   = t >> 2;                   // pixel-slot within tile (0..63)

  const float dtb = dt[b];
  const float* fl = flow + (size_t)b * 2 * H * W;

  // ---- per-pixel coordinate math for PIX pixels ----
  unsigned o00[PIX], o01[PIX], o10[PIX], o11[PIX], oou[PIX];
  float w00[PIX], w01[PIX], w10[PIX], w11[PIX];
#pragma unroll
  for (int q = 0; q < PIX; ++q) {
    const int pix = tile * PPB + q * 64 + p;   // 0..16383 within plane
    const int x = pix & (W - 1);
    const int y = pix >> 7;

    const float f0 = fl[y * W + x];
    const float f1 = fl[H * W + y * W + x];

    const float bx = -1.0f + 2.0f * (float)x / (float)(W - 1);
    const float by = -1.0f + 2.0f * (float)y / (float)(H - 1);
    const float gx = bx - f0 * dtb;
    const float gy = by - f1 * dtb;
    float ix = ((gx + 1.0f) * (float)W - 1.0f) * 0.5f;
    float iy = ((gy + 1.0f) * (float)H - 1.0f) * 0.5f;
    ix = fminf(fmaxf(ix, 0.0f), (float)(W - 1));
    iy = fminf(fmaxf(iy, 0.0f), (float)(H - 1));

    const float x0f = floorf(ix);
    const float y0f = floorf(iy);
    const float wx = ix - x0f;
    const float wy = iy - y0f;
    const int x0 = min(max((int)x0f, 0), W - 1);
    const int x1 = min(x0 + 1, W - 1);
    const int y0 = min(max((int)y0f, 0), H - 1);
    const int y1 = min(y0 + 1, H - 1);

    w00[q] = (1.0f - wx) * (1.0f - wy);
    w01[q] = wx * (1.0f - wy);
    w10[q] = (1.0f - wx) * wy;
    w11[q] = wx * wy;

    o00[q] = (unsigned)(y0 * W + x0) * R + r4;
    o01[q] = (unsigned)(y0 * W + x1) * R + r4;
    o10[q] = (unsigned)(y1 * W + x0) * R + r4;
    o11[q] = (unsigned)(y1 * W + x1) * R + r4;
    oou[q] = (unsigned)pix * R + r4;
  }

  const size_t chwr = (size_t)H * W * R;
  const size_t base = ((size_t)b * C + c0) * chwr;   // block-uniform -> SGPR

  // ---- 16 independent gathers, ALL issued before the fence ----
  nfloat4 v[PIX][CH][4];
#pragma unroll
  for (int q = 0; q < PIX; ++q) {
#pragma unroll
    for (int cc = 0; cc < CH; ++cc) {
      const float* cb = h_prev + base + (size_t)cc * chwr;
      v[q][cc][0] = *(const nfloat4*)(cb + o00[q]);
      v[q][cc][1] = *(const nfloat4*)(cb + o01[q]);
      v[q][cc][2] = *(const nfloat4*)(cb + o10[q]);
      v[q][cc][3] = *(const nfloat4*)(cb + o11[q]);
    }
  }

  // Scheduling fence: nothing crosses. Forces all 16 load results live
  // simultaneously -> real MLP instead of register-reuse serialization.
  __builtin_amdgcn_sched_barrier(0);

  // ---- blend + coalesced NT stores ----
#pragma unroll
  for (int q = 0; q < PIX; ++q) {
#pragma unroll
    for (int cc = 0; cc < CH; ++cc) {
      nfloat4 r = v[q][cc][0] * w00[q] + v[q][cc][1] * w01[q] +
                  v[q][cc][2] * w10[q] + v[q][cc][3] * w11[q];
      __builtin_nontemporal_store(
          r, (nfloat4*)(out + base + (size_t)cc * chwr + oou[q]));
    }
  }
}

extern "C" void kernel_launch(void* const* d_in, const int* in_sizes, int n_in,
                              void* d_out, int out_size, void* d_ws, size_t ws_size,
                              hipStream_t stream) {
  const float* h_prev = (const float*)d_in[0];
  const float* flow   = (const float*)d_in[1];
  const float* dt     = (const float*)d_in[2];
  float* outp = (float*)d_out;

  const int grid = GROUPS * TILES;   // 16384 blocks
  lie_transport_kernel<<<grid, 256, 0, stream>>>(h_prev, flow, dt, outp);
}